// Round 2
// baseline (578.394 us; speedup 1.0000x reference)
//
#include <hip/hip_runtime.h>
#include <hip/hip_bf16.h>

#define B  2048
#define DX 64
#define DH 128
#define DA 128
#define T  256

typedef __attribute__((ext_vector_type(8))) short bf16x8;
typedef __attribute__((ext_vector_type(4))) float f32x4;

__device__ inline unsigned short bfbits(float f) {
    unsigned int u = __float_as_uint(f);
    unsigned int r = (u + 0x7fffu + ((u >> 16) & 1u)) >> 16;
    return (unsigned short)r;
}

__device__ inline float fast_tanh(float x) {
    x = fminf(15.f, fmaxf(-15.f, x));
    float e = __expf(2.f * x);
    return 1.f - 2.f * __builtin_amdgcn_rcpf(e + 1.f);
}

__device__ inline float sigm(float x) {
    return __builtin_amdgcn_rcpf(1.f + __expf(-x));
}

// ---------------------------------------------------------------------------
// K0: W_ah [d][a] fp32 -> wT [a][d] bf16
// ---------------------------------------------------------------------------
__global__ void k0_wt(const float* __restrict__ Wah, unsigned short* __restrict__ wT) {
    int i = blockIdx.x * 256 + threadIdx.x;   // 0..DA*DH-1
    int d = i >> 7;
    int a = i & 127;
    wT[a * DH + d] = bfbits(Wah[i]);
}

// ---------------------------------------------------------------------------
// K1: gates -> new_c (out), h, q, g (ws).  512 thr, 8 rows/block, grid B/8.
// ---------------------------------------------------------------------------
__global__ __launch_bounds__(512) void k1_gates(
    const float* __restrict__ xx,  const float* __restrict__ ph,
    const float* __restrict__ pcv, const float* __restrict__ dtv,
    const float* __restrict__ Wsx, const float* __restrict__ Wsh, const float* __restrict__ wst, const float* __restrict__ bs,
    const float* __restrict__ Wfx, const float* __restrict__ Wfh, const float* __restrict__ Wfs, const float* __restrict__ bf_,
    const float* __restrict__ Wix, const float* __restrict__ Wih, const float* __restrict__ Wis, const float* __restrict__ bi_,
    const float* __restrict__ WTx, const float* __restrict__ WTh, const float* __restrict__ WTs, const float* __restrict__ bT_,
    const float* __restrict__ Wex, const float* __restrict__ Weh, const float* __restrict__ Wes, const float* __restrict__ be_,
    const float* __restrict__ Wox, const float* __restrict__ Woh, const float* __restrict__ Wos, const float* __restrict__ bo_,
    const float* __restrict__ Waq, const float* __restrict__ Wak, const float* __restrict__ Whg,
    float* __restrict__ outc, float* __restrict__ wsh, float* __restrict__ wsq, float* __restrict__ wsg)
{
    __shared__ float shh[8][DH], shx[8][DX], shs[8][DH], shc[8][DH], shn[8][DH];
    const int tid = threadIdx.x;
    const int c   = tid & 127;
    const int qd  = tid >> 7;        // 0..3
    const int r0  = blockIdx.x * 8;
    const int ra  = qd * 2, rb = qd * 2 + 1;

    for (int i = tid; i < 8 * DH; i += 512) shh[i >> 7][i & 127] = ph[(size_t)r0 * DH + i];
    for (int i = tid; i < 8 * DX; i += 512) shx[i >> 6][i & 63]  = xx[(size_t)r0 * DX + i];
    __syncthreads();

    float A0, A1;
    // gate s
    {
        float bb = bs[c], w0 = wst[c];
        A0 = bb + dtv[r0 + ra] * w0;
        A1 = bb + dtv[r0 + rb] * w0;
        for (int k = 0; k < DH; ++k) { float wv = Wsh[k * DH + c]; A0 += shh[ra][k] * wv; A1 += shh[rb][k] * wv; }
        for (int k = 0; k < DX; ++k) { float wv = Wsx[k * DH + c]; A0 += shx[ra][k] * wv; A1 += shx[rb][k] * wv; }
        shs[ra][c] = fast_tanh(A0);
        shs[rb][c] = fast_tanh(A1);
    }
    __syncthreads();

#define G3(Wh_, Wx_, Ws_, b_)                                                              \
    { float bb = (b_)[c]; A0 = bb; A1 = bb;                                                \
      for (int k = 0; k < DH; ++k) { float wv = (Wh_)[k * DH + c];                         \
          A0 += shh[ra][k] * wv; A1 += shh[rb][k] * wv; }                                  \
      for (int k = 0; k < DX; ++k) { float wv = (Wx_)[k * DH + c];                         \
          A0 += shx[ra][k] * wv; A1 += shx[rb][k] * wv; }                                  \
      for (int k = 0; k < DH; ++k) { float wv = (Ws_)[k * DH + c];                         \
          A0 += shs[ra][k] * wv; A1 += shs[rb][k] * wv; } }

    G3(Wfh, Wfx, Wfs, bf_); float f0 = sigm(A0), f1 = sigm(A1);
    G3(Wih, Wix, Wis, bi_); float i0 = sigm(A0), i1 = sigm(A1);
    G3(WTh, WTx, WTs, bT_); float t0 = sigm(A0), t1 = sigm(A1);
    G3(Weh, Wex, Wes, be_); float e0 = fast_tanh(A0), e1 = fast_tanh(A1);
    G3(Woh, Wox, Wos, bo_); float o0 = sigm(A0), o1 = sigm(A1);
#undef G3

    {
        float s0 = shs[ra][c], s1 = shs[rb][c];
        float c0 = f0 * pcv[(size_t)(r0 + ra) * DH + c] + i0 * e0 + t0 * s0;
        float c1 = f1 * pcv[(size_t)(r0 + rb) * DH + c] + i1 * e1 + t1 * s1;
        float h0 = o0 * sigm(c0);
        float h1 = o1 * sigm(c1);
        outc[(size_t)(r0 + ra) * DH + c] = c0;
        outc[(size_t)(r0 + rb) * DH + c] = c1;
        wsh[(size_t)(r0 + ra) * DH + c] = h0;
        wsh[(size_t)(r0 + rb) * DH + c] = h1;
        shc[ra][c] = c0; shc[rb][c] = c1;
        shn[ra][c] = h0; shn[rb][c] = h1;
    }
    // g = sigmoid(x @ W_hg)
    {
        A0 = 0.f; A1 = 0.f;
        for (int k = 0; k < DX; ++k) { float wv = Whg[k * DH + c]; A0 += shx[ra][k] * wv; A1 += shx[rb][k] * wv; }
        wsg[(size_t)(r0 + ra) * DH + c] = sigm(A0);
        wsg[(size_t)(r0 + rb) * DH + c] = sigm(A1);
    }
    __syncthreads();
    // q = h @ W_aq + new_c @ W_ak
    {
        A0 = 0.f; A1 = 0.f;
        for (int k = 0; k < DH; ++k) {
            float wq_ = Waq[k * DH + c], wk_ = Wak[k * DH + c];
            A0 += shn[ra][k] * wq_ + shc[ra][k] * wk_;
            A1 += shn[rb][k] * wq_ + shc[rb][k] * wk_;
        }
        wsq[(size_t)(r0 + ra) * DH + c] = A0;
        wsq[(size_t)(r0 + rb) * DH + c] = A1;
    }
}

// ---------------------------------------------------------------------------
// K2: attention per batch row. 256 thr (4 waves), grid B.
// ---------------------------------------------------------------------------
__global__ __launch_bounds__(256, 2) void k2_attn(
    const float* __restrict__ store_, const unsigned short* __restrict__ wt,
    const float* __restrict__ ba, const float* __restrict__ va,
    const float* __restrict__ wsq, float* __restrict__ wsctx)
{
    __shared__ __align__(16) unsigned short ldsA[64][136];  // 64 x 128 bf16, padded pitch
    __shared__ float qb[DA], vv[DA], ee[T], red[8], ctxh[2][DH];

    const int tid = threadIdx.x;
    const int r   = blockIdx.x;
    const int l   = tid & 63;
    const int w   = tid >> 6;      // wave 0..3
    const int lr  = l & 15;
    const int kg  = l >> 4;        // 0..3
    const float* srow = store_ + (size_t)r * (T * DH);

    if (tid < DA) {
        qb[tid] = wsq[(size_t)r * DA + tid] + ba[tid];
        vv[tid] = va[tid];
    }

    // register-cache all B fragments of W_ahT (same for every tile)
    bf16x8 bfr[8][4];
#pragma unroll
    for (int ct = 0; ct < 8; ++ct)
#pragma unroll
        for (int ks = 0; ks < 4; ++ks)
            bfr[ct][ks] = *(const bf16x8*)&wt[(ct * 16 + lr) * DH + ks * 32 + kg * 8];

    for (int tt = 0; tt < 4; ++tt) {
        __syncthreads();   // protect ldsA from previous tile's readers
#pragma unroll
        for (int ci = 0; ci < 4; ++ci) {
            int cid = tid + ci * 256;        // 0..1023
            int row = cid >> 4;              // 0..63
            int c8  = cid & 15;
            const float* g = srow + ((tt * 64 + row) * DH + c8 * 8);
            float4 u0 = *(const float4*)g;
            float4 u1 = *(const float4*)(g + 4);
            union { unsigned short us[8]; uint4 v; } pk;
            pk.us[0] = bfbits(u0.x); pk.us[1] = bfbits(u0.y);
            pk.us[2] = bfbits(u0.z); pk.us[3] = bfbits(u0.w);
            pk.us[4] = bfbits(u1.x); pk.us[5] = bfbits(u1.y);
            pk.us[6] = bfbits(u1.z); pk.us[7] = bfbits(u1.w);
            *(uint4*)&ldsA[row][c8 * 8] = pk.v;
        }
        __syncthreads();

        f32x4 acc[8];
#pragma unroll
        for (int ct = 0; ct < 8; ++ct) acc[ct] = (f32x4){0.f, 0.f, 0.f, 0.f};
        const int arow = w * 16 + lr;
#pragma unroll
        for (int ks = 0; ks < 4; ++ks) {
            bf16x8 af = *(const bf16x8*)&ldsA[arow][ks * 32 + kg * 8];
#pragma unroll
            for (int ct = 0; ct < 8; ++ct)
                acc[ct] = __builtin_amdgcn_mfma_f32_16x16x32_bf16(af, bfr[ct][ks], acc[ct], 0, 0, 0);
        }

        // e partials: e[t] = sum_a v[a] * tanh(qb[a] + key[t][a])
        float pe[4] = {0.f, 0.f, 0.f, 0.f};
#pragma unroll
        for (int ct = 0; ct < 8; ++ct) {
            int a = ct * 16 + lr;
            float qa = qb[a], vva = vv[a];
#pragma unroll
            for (int reg = 0; reg < 4; ++reg)
                pe[reg] += vva * fast_tanh(qa + acc[ct][reg]);
        }
#pragma unroll
        for (int m = 1; m <= 8; m <<= 1) {
#pragma unroll
            for (int reg = 0; reg < 4; ++reg) pe[reg] += __shfl_xor(pe[reg], m);
        }
        if (lr == 0) {
#pragma unroll
            for (int reg = 0; reg < 4; ++reg)
                ee[tt * 64 + w * 16 + kg * 4 + reg] = pe[reg];
        }
    }
    __syncthreads();

    // softmax over ee[256]
    float xv = ee[tid];
    float mx = xv;
#pragma unroll
    for (int m = 1; m < 64; m <<= 1) mx = fmaxf(mx, __shfl_xor(mx, m));
    if (l == 0) red[w] = mx;
    __syncthreads();
    float M = fmaxf(fmaxf(red[0], red[1]), fmaxf(red[2], red[3]));
    float ex = __expf(xv - M);
    float sm = ex;
#pragma unroll
    for (int m = 1; m < 64; m <<= 1) sm += __shfl_xor(sm, m);
    if (l == 0) red[4 + w] = sm;
    __syncthreads();
    float S = red[4] + red[5] + red[6] + red[7];
    ee[tid] = ex / S;     // alpha
    __syncthreads();

    // ctx = sum_t alpha[t] * store[r, t, :]   (row is L2-warm)
    {
        int d = tid & 127, th = tid >> 7;
        const float* sp = srow + (size_t)th * 128 * DH + d;
        float p = 0.f;
        for (int t = 0; t < 128; ++t) p = fmaf(ee[th * 128 + t], sp[(size_t)t * DH], p);
        ctxh[th][d] = p;
    }
    __syncthreads();
    if (tid < DH) wsctx[(size_t)r * DH + tid] = ctxh[0][tid] + ctxh[1][tid];
}

// ---------------------------------------------------------------------------
// K3: new_h = g * tanh(h @ W_hh + ctx @ W_he + b_h).  512 thr, 8 rows/block.
// ---------------------------------------------------------------------------
__global__ __launch_bounds__(512) void k3_inter(
    const float* __restrict__ wsh, const float* __restrict__ wsctx, const float* __restrict__ wsg,
    const float* __restrict__ Whh, const float* __restrict__ Whe, const float* __restrict__ bh,
    float* __restrict__ outh)
{
    __shared__ float sh[8][DH], sc[8][DH];
    const int tid = threadIdx.x;
    const int c   = tid & 127;
    const int qd  = tid >> 7;
    const int r0  = blockIdx.x * 8;
    const int ra  = qd * 2, rb = qd * 2 + 1;

    for (int i = tid; i < 8 * DH; i += 512) {
        sh[i >> 7][i & 127] = wsh[(size_t)r0 * DH + i];
        sc[i >> 7][i & 127] = wsctx[(size_t)r0 * DH + i];
    }
    __syncthreads();

    float A0 = bh[c], A1 = bh[c];
    for (int k = 0; k < DH; ++k) {
        float wh_ = Whh[k * DH + c], we_ = Whe[k * DH + c];
        A0 += sh[ra][k] * wh_ + sc[ra][k] * we_;
        A1 += sh[rb][k] * wh_ + sc[rb][k] * we_;
    }
    outh[(size_t)(r0 + ra) * DH + c] = wsg[(size_t)(r0 + ra) * DH + c] * fast_tanh(A0);
    outh[(size_t)(r0 + rb) * DH + c] = wsg[(size_t)(r0 + rb) * DH + c] * fast_tanh(A1);
}

// ---------------------------------------------------------------------------
extern "C" void kernel_launch(void* const* d_in, const int* in_sizes, int n_in,
                              void* d_out, int out_size, void* d_ws, size_t ws_size,
                              hipStream_t stream)
{
    const float* x_t   = (const float*)d_in[0];
    const float* ph    = (const float*)d_in[1];
    const float* pc    = (const float*)d_in[2];
    const float* dt    = (const float*)d_in[3];
    const float* store = (const float*)d_in[4];
    const float* Wsx = (const float*)d_in[5];  const float* Wsh = (const float*)d_in[6];
    const float* wst = (const float*)d_in[7];  const float* bs  = (const float*)d_in[8];
    const float* Wfx = (const float*)d_in[9];  const float* Wfh = (const float*)d_in[10];
    const float* Wfs = (const float*)d_in[11]; const float* bf_ = (const float*)d_in[12];
    const float* Wix = (const float*)d_in[13]; const float* Wih = (const float*)d_in[14];
    const float* Wis = (const float*)d_in[15]; const float* bi_ = (const float*)d_in[16];
    const float* WTx = (const float*)d_in[17]; const float* WTh = (const float*)d_in[18];
    const float* WTs = (const float*)d_in[19]; const float* bT_ = (const float*)d_in[20];
    const float* Wex = (const float*)d_in[21]; const float* Weh = (const float*)d_in[22];
    const float* Wes = (const float*)d_in[23]; const float* be_ = (const float*)d_in[24];
    const float* Wox = (const float*)d_in[25]; const float* Woh = (const float*)d_in[26];
    const float* Wos = (const float*)d_in[27]; const float* bo_ = (const float*)d_in[28];
    const float* Waq = (const float*)d_in[29]; const float* Wak = (const float*)d_in[30];
    const float* Wah = (const float*)d_in[31]; const float* ba  = (const float*)d_in[32];
    const float* va  = (const float*)d_in[33];
    const float* Whh = (const float*)d_in[34]; const float* Whe = (const float*)d_in[35];
    const float* Whg = (const float*)d_in[36]; const float* bh  = (const float*)d_in[37];

    float* outc = (float*)d_out;
    float* outh = outc + (size_t)B * DH;

    float* wsh   = (float*)d_ws;
    float* wsq   = wsh + (size_t)B * DH;
    float* wsg   = wsq + (size_t)B * DH;
    float* wsctx = wsg + (size_t)B * DH;
    unsigned short* wT = (unsigned short*)(wsctx + (size_t)B * DH);

    k0_wt<<<(DA * DH) / 256, 256, 0, stream>>>(Wah, wT);
    k1_gates<<<B / 8, 512, 0, stream>>>(x_t, ph, pc, dt,
                                        Wsx, Wsh, wst, bs,
                                        Wfx, Wfh, Wfs, bf_,
                                        Wix, Wih, Wis, bi_,
                                        WTx, WTh, WTs, bT_,
                                        Wex, Weh, Wes, be_,
                                        Wox, Woh, Wos, bo_,
                                        Waq, Wak, Whg,
                                        outc, wsh, wsq, wsg);
    k2_attn<<<B, 256, 0, stream>>>(store, wT, ba, va, wsq, wsctx);
    k3_inter<<<B / 8, 512, 0, stream>>>(wsh, wsctx, wsg, Whh, Whe, bh, outh);
}

// Round 3
// 571.858 us; speedup vs baseline: 1.0114x; 1.0114x over previous
//
#include <hip/hip_runtime.h>
#include <hip/hip_bf16.h>

#define B  2048
#define DX 64
#define DH 128
#define DA 128
#define T  256

typedef __attribute__((ext_vector_type(8))) short bf16x8;
typedef __attribute__((ext_vector_type(4))) float f32x4;

__device__ inline unsigned short bfbits(float f) {
    unsigned int u = __float_as_uint(f);
    unsigned int r = (u + 0x7fffu + ((u >> 16) & 1u)) >> 16;
    return (unsigned short)r;
}
__device__ inline float bf2f(unsigned short s) {
    return __uint_as_float(((unsigned int)s) << 16);
}
__device__ inline float fast_tanh(float x) {
    x = fminf(15.f, fmaxf(-15.f, x));
    float e = __expf(2.f * x);
    return 1.f - 2.f * __builtin_amdgcn_rcpf(e + 1.f);
}
__device__ inline float sigm(float x) {
    return __builtin_amdgcn_rcpf(1.f + __expf(-x));
}
// wave-uniform broadcast of lane k's value -> SGPR (no LDS, feeds FMA as s-operand)
__device__ inline float RL(float v, int k) {
    return __int_as_float(__builtin_amdgcn_readlane(__float_as_int(v), k));
}

// ---------------------------------------------------------------------------
// K0: W_ah [d][a] fp32 -> wT [a][d] bf16
// ---------------------------------------------------------------------------
__global__ void k0_wt(const float* __restrict__ Wah, unsigned short* __restrict__ wT) {
    int i = blockIdx.x * 256 + threadIdx.x;
    int d = i >> 7;
    int a = i & 127;
    wT[a * DH + d] = bfbits(Wah[i]);
}

// ---------------------------------------------------------------------------
// K1: gates. 256 thr (4 waves), 8 rows/block, 4 rows/thread, grid 256.
// Activations in registers, broadcast via v_readlane; weights streamed from L2.
// ---------------------------------------------------------------------------
__global__ __launch_bounds__(256) void k1_gates(
    const float* __restrict__ xx,  const float* __restrict__ ph,
    const float* __restrict__ pcv, const float* __restrict__ dtv,
    const float* __restrict__ Wsx, const float* __restrict__ Wsh, const float* __restrict__ wst, const float* __restrict__ bs,
    const float* __restrict__ Wfx, const float* __restrict__ Wfh, const float* __restrict__ Wfs, const float* __restrict__ bf_,
    const float* __restrict__ Wix, const float* __restrict__ Wih, const float* __restrict__ Wis, const float* __restrict__ bi_,
    const float* __restrict__ WTx, const float* __restrict__ WTh, const float* __restrict__ WTs, const float* __restrict__ bT_,
    const float* __restrict__ Wex, const float* __restrict__ Weh, const float* __restrict__ Wes, const float* __restrict__ be_,
    const float* __restrict__ Wox, const float* __restrict__ Woh, const float* __restrict__ Wos, const float* __restrict__ bo_,
    const float* __restrict__ Waq, const float* __restrict__ Wak, const float* __restrict__ Whg,
    float* __restrict__ outc, float* __restrict__ wsh, float* __restrict__ wsq, float* __restrict__ wsg)
{
    __shared__ float shs[8][DH], shc[8][DH], shn[8][DH];
    const int tid = threadIdx.x;
    const int l   = tid & 63;
    const int w   = tid >> 6;          // 0..3
    const int rg  = w >> 1;            // 0..1 : which 4-row group
    const int c   = (w & 1) * 64 + l;  // output column
    const int r0  = blockIdx.x * 8;
    const int rbase = r0 + rg * 4;

    float hL[4], hH[4], xr[4], dts[4];
#pragma unroll
    for (int i = 0; i < 4; ++i) {
        hL[i]  = ph[(size_t)(rbase + i) * DH + l];
        hH[i]  = ph[(size_t)(rbase + i) * DH + 64 + l];
        xr[i]  = xx[(size_t)(rbase + i) * DX + l];
        dts[i] = dtv[rbase + i];
    }

    float A[4], sv[4];
    // ---- gate s ----
    {
        float bb = bs[c], w0 = wst[c];
#pragma unroll
        for (int i = 0; i < 4; ++i) A[i] = bb + dts[i] * w0;
#pragma unroll 8
        for (int k = 0; k < 64; ++k) { float wv = Wsh[k * DH + c];
#pragma unroll
            for (int i = 0; i < 4; ++i) A[i] = fmaf(RL(hL[i], k), wv, A[i]); }
#pragma unroll 8
        for (int k = 0; k < 64; ++k) { float wv = Wsh[(k + 64) * DH + c];
#pragma unroll
            for (int i = 0; i < 4; ++i) A[i] = fmaf(RL(hH[i], k), wv, A[i]); }
#pragma unroll 8
        for (int k = 0; k < 64; ++k) { float wv = Wsx[k * DH + c];
#pragma unroll
            for (int i = 0; i < 4; ++i) A[i] = fmaf(RL(xr[i], k), wv, A[i]); }
#pragma unroll
        for (int i = 0; i < 4; ++i) { sv[i] = fast_tanh(A[i]); shs[rg * 4 + i][c] = sv[i]; }
    }
    __syncthreads();
    float sL[4], sH[4];
#pragma unroll
    for (int i = 0; i < 4; ++i) { sL[i] = shs[rg * 4 + i][l]; sH[i] = shs[rg * 4 + i][64 + l]; }

#define G3(Wh_, Wx_, Ws_, b_)                                                   \
    { float bb = (b_)[c];                                                       \
      _Pragma("unroll") for (int i = 0; i < 4; ++i) A[i] = bb;                  \
      _Pragma("unroll 8") for (int k = 0; k < 64; ++k) {                        \
          float wv = (Wh_)[k * DH + c];                                         \
          _Pragma("unroll") for (int i = 0; i < 4; ++i)                         \
              A[i] = fmaf(RL(hL[i], k), wv, A[i]); }                            \
      _Pragma("unroll 8") for (int k = 0; k < 64; ++k) {                        \
          float wv = (Wh_)[(k + 64) * DH + c];                                  \
          _Pragma("unroll") for (int i = 0; i < 4; ++i)                         \
              A[i] = fmaf(RL(hH[i], k), wv, A[i]); }                            \
      _Pragma("unroll 8") for (int k = 0; k < 64; ++k) {                        \
          float wv = (Wx_)[k * DH + c];                                         \
          _Pragma("unroll") for (int i = 0; i < 4; ++i)                         \
              A[i] = fmaf(RL(xr[i], k), wv, A[i]); }                            \
      _Pragma("unroll 8") for (int k = 0; k < 64; ++k) {                        \
          float wv = (Ws_)[k * DH + c];                                         \
          _Pragma("unroll") for (int i = 0; i < 4; ++i)                         \
              A[i] = fmaf(RL(sL[i], k), wv, A[i]); }                            \
      _Pragma("unroll 8") for (int k = 0; k < 64; ++k) {                        \
          float wv = (Ws_)[(k + 64) * DH + c];                                  \
          _Pragma("unroll") for (int i = 0; i < 4; ++i)                         \
              A[i] = fmaf(RL(sH[i], k), wv, A[i]); } }

    float fg[4], ig[4], tg[4], eg[4], og[4];
    G3(Wfh, Wfx, Wfs, bf_);
#pragma unroll
    for (int i = 0; i < 4; ++i) fg[i] = sigm(A[i]);
    G3(Wih, Wix, Wis, bi_);
#pragma unroll
    for (int i = 0; i < 4; ++i) ig[i] = sigm(A[i]);
    G3(WTh, WTx, WTs, bT_);
#pragma unroll
    for (int i = 0; i < 4; ++i) tg[i] = sigm(A[i]);
    G3(Weh, Wex, Wes, be_);
#pragma unroll
    for (int i = 0; i < 4; ++i) eg[i] = fast_tanh(A[i]);
    G3(Woh, Wox, Wos, bo_);
#pragma unroll
    for (int i = 0; i < 4; ++i) og[i] = sigm(A[i]);
#undef G3

    // elementwise: new_c, h
#pragma unroll
    for (int i = 0; i < 4; ++i) {
        float cn = fg[i] * pcv[(size_t)(rbase + i) * DH + c] + ig[i] * eg[i] + tg[i] * sv[i];
        float hn = og[i] * sigm(cn);
        outc[(size_t)(rbase + i) * DH + c] = cn;
        wsh [(size_t)(rbase + i) * DH + c] = hn;
        shc[rg * 4 + i][c] = cn;
        shn[rg * 4 + i][c] = hn;
    }
    // g = sigmoid(x @ W_hg)
    {
#pragma unroll
        for (int i = 0; i < 4; ++i) A[i] = 0.f;
#pragma unroll 8
        for (int k = 0; k < 64; ++k) { float wv = Whg[k * DH + c];
#pragma unroll
            for (int i = 0; i < 4; ++i) A[i] = fmaf(RL(xr[i], k), wv, A[i]); }
#pragma unroll
        for (int i = 0; i < 4; ++i) wsg[(size_t)(rbase + i) * DH + c] = sigm(A[i]);
    }
    __syncthreads();
    // q = h_new @ W_aq + c_new @ W_ak
    {
        float nL[4], nH[4], cL[4], cH[4];
#pragma unroll
        for (int i = 0; i < 4; ++i) {
            nL[i] = shn[rg * 4 + i][l]; nH[i] = shn[rg * 4 + i][64 + l];
            cL[i] = shc[rg * 4 + i][l]; cH[i] = shc[rg * 4 + i][64 + l];
        }
#pragma unroll
        for (int i = 0; i < 4; ++i) A[i] = 0.f;
#pragma unroll 8
        for (int k = 0; k < 64; ++k) {
            float wq = Waq[k * DH + c], wk2 = Wak[k * DH + c];
#pragma unroll
            for (int i = 0; i < 4; ++i)
                A[i] = fmaf(RL(nL[i], k), wq, fmaf(RL(cL[i], k), wk2, A[i]));
        }
#pragma unroll 8
        for (int k = 0; k < 64; ++k) {
            float wq = Waq[(k + 64) * DH + c], wk2 = Wak[(k + 64) * DH + c];
#pragma unroll
            for (int i = 0; i < 4; ++i)
                A[i] = fmaf(RL(nH[i], k), wq, fmaf(RL(cH[i], k), wk2, A[i]));
        }
#pragma unroll
        for (int i = 0; i < 4; ++i) wsq[(size_t)(rbase + i) * DH + c] = A[i];
    }
}

// ---------------------------------------------------------------------------
// K2: attention per batch row, single store pass, double-buffered LDS,
// online exp-weighted ctx (no max subtraction: |e| <= ||v||_1 ~ 5).
// ---------------------------------------------------------------------------
__global__ __launch_bounds__(256, 2) void k2_attn(
    const float* __restrict__ store_, const unsigned short* __restrict__ wt,
    const float* __restrict__ ba, const float* __restrict__ va,
    const float* __restrict__ wsq, float* __restrict__ wsctx)
{
    __shared__ __align__(16) unsigned short buf[2][64][136];  // 34.8 KB
    __shared__ float qb[DA], vv[DA], ee[T], red[8], ctxh[2][DH];

    const int tid = threadIdx.x;
    const int r   = blockIdx.x;
    const int l   = tid & 63;
    const int w   = tid >> 6;      // wave 0..3
    const int lr  = l & 15;
    const int kg  = l >> 4;        // 0..3
    const int d   = tid & 127;
    const int th  = tid >> 7;      // 0..1
    const float* srow = store_ + (size_t)r * (T * DH);

    if (tid < DA) {
        qb[tid] = wsq[(size_t)r * DA + tid] + ba[tid];
        vv[tid] = va[tid];
    }

    // register-cache all B fragments of W_ahT (reused by all 4 tiles)
    bf16x8 bfr[8][4];
#pragma unroll
    for (int ct = 0; ct < 8; ++ct)
#pragma unroll
        for (int ks = 0; ks < 4; ++ks)
            bfr[ct][ks] = *(const bf16x8*)&wt[(ct * 16 + lr) * DH + ks * 32 + kg * 8];

    float4 ra_[4], rb_[4];
#define STAGE_LOAD(tt)                                                     \
    _Pragma("unroll")                                                      \
    for (int ci = 0; ci < 4; ++ci) {                                       \
        int cid = tid + ci * 256;                                          \
        int row = cid >> 4, c8 = cid & 15;                                 \
        const float* g = srow + ((tt) * 64 + row) * DH + c8 * 8;           \
        ra_[ci] = *(const float4*)g;                                       \
        rb_[ci] = *(const float4*)(g + 4);                                 \
    }
#define STAGE_WRITE(bsel)                                                  \
    _Pragma("unroll")                                                      \
    for (int ci = 0; ci < 4; ++ci) {                                       \
        int cid = tid + ci * 256;                                          \
        int row = cid >> 4, c8 = cid & 15;                                 \
        union { unsigned short us[8]; uint4 v; } pk;                       \
        pk.us[0] = bfbits(ra_[ci].x); pk.us[1] = bfbits(ra_[ci].y);        \
        pk.us[2] = bfbits(ra_[ci].z); pk.us[3] = bfbits(ra_[ci].w);        \
        pk.us[4] = bfbits(rb_[ci].x); pk.us[5] = bfbits(rb_[ci].y);        \
        pk.us[6] = bfbits(rb_[ci].z); pk.us[7] = bfbits(rb_[ci].w);        \
        *(uint4*)&buf[bsel][row][c8 * 8] = pk.v;                           \
    }

    STAGE_LOAD(0);
    STAGE_WRITE(0);

    float Sw   = 0.f;   // partial denominator (on lr==0 lanes)
    float oacc = 0.f;   // ctx numerator partial: this thread's (th, d)

    for (int tt = 0; tt < 4; ++tt) {
        const int cur = tt & 1;
        if (tt < 3) STAGE_LOAD(tt + 1);          // HBM loads fly under compute
        __syncthreads();                          // buf[cur] writes visible

        f32x4 acc[8];
#pragma unroll
        for (int ct = 0; ct < 8; ++ct) acc[ct] = (f32x4){0.f, 0.f, 0.f, 0.f};
        const int arow = w * 16 + lr;
#pragma unroll
        for (int ks = 0; ks < 4; ++ks) {
            bf16x8 af = *(const bf16x8*)&buf[cur][arow][ks * 32 + kg * 8];
#pragma unroll
            for (int ct = 0; ct < 8; ++ct)
                acc[ct] = __builtin_amdgcn_mfma_f32_16x16x32_bf16(af, bfr[ct][ks], acc[ct], 0, 0, 0);
        }

        // e[t] = sum_a v[a] * tanh(qb[a] + key[t][a]); reduce over lr (16 a's each)
        float pe[4] = {0.f, 0.f, 0.f, 0.f};
#pragma unroll
        for (int ct = 0; ct < 8; ++ct) {
            int a = ct * 16 + lr;
            float qa = qb[a], vva = vv[a];
#pragma unroll
            for (int reg = 0; reg < 4; ++reg)
                pe[reg] += vva * fast_tanh(qa + acc[ct][reg]);
        }
#pragma unroll
        for (int m = 1; m <= 8; m <<= 1) {
#pragma unroll
            for (int reg = 0; reg < 4; ++reg) pe[reg] += __shfl_xor(pe[reg], m);
        }
        // p = exp(e) directly (|e| bounded ~5) ; t = tt*64 + w*16 + kg*4 + reg
        float px[4];
#pragma unroll
        for (int reg = 0; reg < 4; ++reg) px[reg] = __expf(pe[reg]);
        if (lr == 0) {
#pragma unroll
            for (int reg = 0; reg < 4; ++reg)
                ee[tt * 64 + w * 16 + kg * 4 + reg] = px[reg];
            Sw += px[0] + px[1] + px[2] + px[3];
        }
        __syncthreads();                          // p-tile visible

        // ctx accumulate from LDS bf16 copy (no second global pass)
#pragma unroll 8
        for (int j = 0; j < 32; ++j) {
            int t = th * 32 + j;
            float p = ee[tt * 64 + t];
            oacc = fmaf(p, bf2f(buf[cur][t][d]), oacc);
        }
        if (tt < 3) STAGE_WRITE((tt + 1) & 1);    // fill other buffer
    }

    // denominator: sum Sw across wave (nonzero on lr==0 lanes), then cross-wave
#pragma unroll
    for (int m = 1; m < 64; m <<= 1) Sw += __shfl_xor(Sw, m);
    if (l == 0) red[w] = Sw;
    ctxh[th][d] = oacc;
    __syncthreads();
    float S = red[0] + red[1] + red[2] + red[3];
    if (tid < DH) wsctx[(size_t)r * DH + tid] = (ctxh[0][tid] + ctxh[1][tid]) / S;
#undef STAGE_LOAD
#undef STAGE_WRITE
}

// ---------------------------------------------------------------------------
// K3: new_h = g * tanh(h @ W_hh + ctx @ W_he + b_h). Same geometry as K1.
// ---------------------------------------------------------------------------
__global__ __launch_bounds__(256) void k3_inter(
    const float* __restrict__ wsh, const float* __restrict__ wsctx, const float* __restrict__ wsg,
    const float* __restrict__ Whh, const float* __restrict__ Whe, const float* __restrict__ bh,
    float* __restrict__ outh)
{
    const int tid = threadIdx.x;
    const int l   = tid & 63;
    const int w   = tid >> 6;
    const int rg  = w >> 1;
    const int c   = (w & 1) * 64 + l;
    const int rbase = blockIdx.x * 8 + rg * 4;

    float hL[4], hH[4], cL[4], cH[4];
#pragma unroll
    for (int i = 0; i < 4; ++i) {
        hL[i] = wsh  [(size_t)(rbase + i) * DH + l];
        hH[i] = wsh  [(size_t)(rbase + i) * DH + 64 + l];
        cL[i] = wsctx[(size_t)(rbase + i) * DH + l];
        cH[i] = wsctx[(size_t)(rbase + i) * DH + 64 + l];
    }
    float A[4];
    float bb = bh[c];
#pragma unroll
    for (int i = 0; i < 4; ++i) A[i] = bb;
#pragma unroll 8
    for (int k = 0; k < 64; ++k) {
        float wh_ = Whh[k * DH + c], we_ = Whe[k * DH + c];
#pragma unroll
        for (int i = 0; i < 4; ++i)
            A[i] = fmaf(RL(hL[i], k), wh_, fmaf(RL(cL[i], k), we_, A[i]));
    }
#pragma unroll 8
    for (int k = 0; k < 64; ++k) {
        float wh_ = Whh[(k + 64) * DH + c], we_ = Whe[(k + 64) * DH + c];
#pragma unroll
        for (int i = 0; i < 4; ++i)
            A[i] = fmaf(RL(hH[i], k), wh_, fmaf(RL(cH[i], k), we_, A[i]));
    }
#pragma unroll
    for (int i = 0; i < 4; ++i)
        outh[(size_t)(rbase + i) * DH + c] =
            wsg[(size_t)(rbase + i) * DH + c] * fast_tanh(A[i]);
}

// ---------------------------------------------------------------------------
extern "C" void kernel_launch(void* const* d_in, const int* in_sizes, int n_in,
                              void* d_out, int out_size, void* d_ws, size_t ws_size,
                              hipStream_t stream)
{
    const float* x_t   = (const float*)d_in[0];
    const float* ph    = (const float*)d_in[1];
    const float* pc    = (const float*)d_in[2];
    const float* dt    = (const float*)d_in[3];
    const float* store = (const float*)d_in[4];
    const float* Wsx = (const float*)d_in[5];  const float* Wsh = (const float*)d_in[6];
    const float* wst = (const float*)d_in[7];  const float* bs  = (const float*)d_in[8];
    const float* Wfx = (const float*)d_in[9];  const float* Wfh = (const float*)d_in[10];
    const float* Wfs = (const float*)d_in[11]; const float* bf_ = (const float*)d_in[12];
    const float* Wix = (const float*)d_in[13]; const float* Wih = (const float*)d_in[14];
    const float* Wis = (const float*)d_in[15]; const float* bi_ = (const float*)d_in[16];
    const float* WTx = (const float*)d_in[17]; const float* WTh = (const float*)d_in[18];
    const float* WTs = (const float*)d_in[19]; const float* bT_ = (const float*)d_in[20];
    const float* Wex = (const float*)d_in[21]; const float* Weh = (const float*)d_in[22];
    const float* Wes = (const float*)d_in[23]; const float* be_ = (const float*)d_in[24];
    const float* Wox = (const float*)d_in[25]; const float* Woh = (const float*)d_in[26];
    const float* Wos = (const float*)d_in[27]; const float* bo_ = (const float*)d_in[28];
    const float* Waq = (const float*)d_in[29]; const float* Wak = (const float*)d_in[30];
    const float* Wah = (const float*)d_in[31]; const float* ba  = (const float*)d_in[32];
    const float* va  = (const float*)d_in[33];
    const float* Whh = (const float*)d_in[34]; const float* Whe = (const float*)d_in[35];
    const float* Whg = (const float*)d_in[36]; const float* bh  = (const float*)d_in[37];

    float* outc = (float*)d_out;
    float* outh = outc + (size_t)B * DH;

    float* wsh   = (float*)d_ws;
    float* wsq   = wsh + (size_t)B * DH;
    float* wsg   = wsq + (size_t)B * DH;
    float* wsctx = wsg + (size_t)B * DH;
    unsigned short* wT = (unsigned short*)(wsctx + (size_t)B * DH);

    k0_wt<<<(DA * DH) / 256, 256, 0, stream>>>(Wah, wT);
    k1_gates<<<B / 8, 256, 0, stream>>>(x_t, ph, pc, dt,
                                        Wsx, Wsh, wst, bs,
                                        Wfx, Wfh, Wfs, bf_,
                                        Wix, Wih, Wis, bi_,
                                        WTx, WTh, WTs, bT_,
                                        Wex, Weh, Wes, be_,
                                        Wox, Woh, Wos, bo_,
                                        Waq, Wak, Whg,
                                        outc, wsh, wsq, wsg);
    k2_attn<<<B, 256, 0, stream>>>(store, wT, ba, va, wsq, wsctx);
    k3_inter<<<B / 8, 256, 0, stream>>>(wsh, wsctx, wsg, Whh, Whe, bh, outh);
}